// Round 5
// baseline (30.789 us; speedup 1.0000x reference)
//
#include <hip/hip_runtime.h>

#define BB 16
#define NN 6000
#define GG 512

// ---- workspace layout ----
// float4 boxes [BB][GG]                : BB*GG*16 bytes
// float  areas [BB][GG] (16B aligned)  : BB*GG*4  bytes
// int    counts[BB][2]                 : BB*8     bytes
#define WS_BOX_OFF   0
#define WS_AREA_OFF  (BB * GG * 16)
#define WS_CNT_OFF   (BB * GG * 20)
#define WS_NEEDED    (WS_CNT_OFF + BB * 8)

__global__ __launch_bounds__(256) void compact_kernel(
    const int*    __restrict__ gt_ids,    // (B, G)
    const float4* __restrict__ gt_boxes,  // (B, G, 4)
    float4*       __restrict__ ws_box,    // (B, G)
    float*        __restrict__ ws_area,   // (B, G)
    int*          __restrict__ ws_cnt)    // (B, 2)
{
    __shared__ int s_cnt[2];
    const int b   = blockIdx.x;
    const int tid = threadIdx.x;
    if (tid == 0) { s_cnt[0] = 0; s_cnt[1] = 0; }
    __syncthreads();

    for (int g = tid; g < GG; g += 256) {
        float4 box = gt_boxes[b * GG + g];
        float asum = fabsf(box.x) + fabsf(box.y) + fabsf(box.z) + fabsf(box.w);
        int id = gt_ids[b * GG + g];
        if (asum > 0.0f && id != 0) {
            int idx;
            if (id > 0) idx = atomicAdd(&s_cnt[0], 1);            // non-crowd: front
            else        idx = (GG - 1) - atomicAdd(&s_cnt[1], 1); // crowd: back
            ws_box[b * GG + idx]  = box;
            ws_area[b * GG + idx] = (box.z - box.x) * (box.w - box.y);
        }
    }
    __syncthreads();
    if (tid == 0) { ws_cnt[b * 2 + 0] = s_cnt[0]; ws_cnt[b * 2 + 1] = s_cnt[1]; }
}

#define WAVES 8
__global__ __launch_bounds__(64 * WAVES) void det_main_kernel(
    const float4* __restrict__ rois,      // (B, N, 4)
    const float4* __restrict__ ws_box,
    const float4* __restrict__ ws_area4,  // (B, G/4) as float4
    const int*    __restrict__ ws_cnt,
    float*        __restrict__ out)
{
    __shared__ float4 s_box[GG];
    __shared__ float4 s_area4[GG / 4];
    __shared__ float  s_ncm[WAVES][64];
    __shared__ float  s_cm[WAVES][64];
    float* s_area = (float*)s_area4;

    const int b    = blockIdx.y;
    const int tid  = threadIdx.x;
    const int wave = tid >> 6;
    const int lane = tid & 63;

    // Branchless staging: copy full compacted arrays (middle garbage never read).
    for (int i = tid; i < GG; i += 64 * WAVES)     s_box[i]   = ws_box[b * GG + i];
    for (int i = tid; i < GG / 4; i += 64 * WAVES) s_area4[i] = ws_area4[b * (GG / 4) + i];
    __syncthreads();

    const int ncnt = ws_cnt[b * 2 + 0];   // uniform address -> s_load
    const int ccnt = ws_cnt[b * 2 + 1];

    const int n = blockIdx.x * 64 + lane;
    const float4 r = (n < NN) ? rois[b * NN + n] : make_float4(0.f, 0.f, 0.f, 0.f);
    const bool vroi = (fabsf(r.x) + fabsf(r.y) + fabsf(r.z) + fabsf(r.w)) > 0.0f;
    const float rsum = (r.z - r.x) * (r.w - r.y) + 1e-8f;

    auto iou_of = [&](float4 gb, float ga) -> float {
        float yy1 = fmaxf(r.x, gb.x);
        float xx1 = fmaxf(r.y, gb.y);
        float yy2 = fminf(r.z, gb.z);
        float xx2 = fminf(r.w, gb.w);
        float inter = fmaxf(yy2 - yy1, 0.0f) * fmaxf(xx2 - xx1, 0.0f);
        float uni = rsum + ga - inter;
        return inter * __builtin_amdgcn_rcpf(uni);
    };

    // --- Non-crowd: wave takes contiguous, 4-aligned chunk of [0, ncnt) ---
    float ncm = 0.0f;
    {
        const int chunk = ((((ncnt + WAVES - 1) / WAVES) + 3) & ~3);
        const int g0 = wave * chunk;
        const int g1 = min(ncnt, g0 + chunk);
        int g = g0;
        for (; g + 4 <= g1; g += 4) {
            float4 b0 = s_box[g + 0];
            float4 b1 = s_box[g + 1];
            float4 b2 = s_box[g + 2];
            float4 b3 = s_box[g + 3];
            float4 a4 = s_area4[g >> 2];
            float i0 = iou_of(b0, a4.x);
            float i1 = iou_of(b1, a4.y);
            float i2 = iou_of(b2, a4.z);
            float i3 = iou_of(b3, a4.w);
            ncm = fmaxf(ncm, fmaxf(fmaxf(i0, i1), fmaxf(i2, i3)));
        }
        for (; g < g1; ++g) ncm = fmaxf(ncm, iou_of(s_box[g], s_area[g]));
    }

    // --- Crowd: list occupies [GG-ccnt, GG); wave takes descending chunk ---
    float cm = 0.0f;
    {
        const int chunkc = ((((ccnt + WAVES - 1) / WAVES) + 3) & ~3);
        const int hi = GG - wave * chunkc;                    // multiple of 4
        const int lo = max(GG - ccnt, hi - chunkc);
        int g = hi;
        while (g - 4 >= lo) {
            g -= 4;
            float4 b0 = s_box[g + 0];
            float4 b1 = s_box[g + 1];
            float4 b2 = s_box[g + 2];
            float4 b3 = s_box[g + 3];
            float4 a4 = s_area4[g >> 2];
            float i0 = iou_of(b0, a4.x);
            float i1 = iou_of(b1, a4.y);
            float i2 = iou_of(b2, a4.z);
            float i3 = iou_of(b3, a4.w);
            cm = fmaxf(cm, fmaxf(fmaxf(i0, i1), fmaxf(i2, i3)));
        }
        while (g > lo) { --g; cm = fmaxf(cm, iou_of(s_box[g], s_area[g])); }
    }

    s_ncm[wave][lane] = ncm;
    s_cm[wave][lane]  = cm;
    __syncthreads();

    if (wave == 0 && n < NN) {
        float a = s_ncm[0][lane], c = s_cm[0][lane];
        #pragma unroll
        for (int w = 1; w < WAVES; ++w) {
            a = fmaxf(a, s_ncm[w][lane]);
            c = fmaxf(c, s_cm[w][lane]);
        }
        const float nc_max = vroi ? a : 0.0f;
        const float c_max  = vroi ? c : 0.0f;

        out[b * 2 * NN + n]      = nc_max;     // iou_maxes (B,2,N) ch0
        out[b * 2 * NN + NN + n] = c_max;      // iou_maxes (B,2,N) ch1
        const float pos = (vroi && nc_max >= 0.5f) ? 1.0f : 0.0f;
        const float neg = (vroi && nc_max < 0.5f && c_max < 0.001f) ? 1.0f : 0.0f;
        out[BB * 2 * NN + b * NN + n]           = pos;
        out[BB * 2 * NN + BB * NN + b * NN + n] = neg;
    }
}

// ---------- fallback (R4): self-contained single kernel ----------
__global__ __launch_bounds__(256) void det_assign_fallback(
    const float4* __restrict__ rois,
    const int*    __restrict__ gt_ids,
    const float4* __restrict__ gt_boxes,
    float*        __restrict__ out)
{
    __shared__ float4 s_box[GG];
    __shared__ float4 s_area4[GG / 4];
    __shared__ float  s_ncm[4][64];
    __shared__ float  s_cm[4][64];
    __shared__ int    s_cnt[2];
    float* s_area = (float*)s_area4;

    const int b    = blockIdx.y;
    const int tid  = threadIdx.x;
    const int wave = tid >> 6;
    const int lane = tid & 63;

    if (tid == 0) { s_cnt[0] = 0; s_cnt[1] = 0; }
    __syncthreads();
    for (int g = tid; g < GG; g += 256) {
        float4 box = gt_boxes[b * GG + g];
        float asum = fabsf(box.x) + fabsf(box.y) + fabsf(box.z) + fabsf(box.w);
        int id = gt_ids[b * GG + g];
        if (asum > 0.0f && id != 0) {
            int idx;
            if (id > 0) idx = atomicAdd(&s_cnt[0], 1);
            else        idx = (GG - 1) - atomicAdd(&s_cnt[1], 1);
            s_box[idx]  = box;
            s_area[idx] = (box.z - box.x) * (box.w - box.y);
        }
    }
    __syncthreads();

    const int n = blockIdx.x * 64 + lane;
    const float4 r = (n < NN) ? rois[b * NN + n] : make_float4(0.f, 0.f, 0.f, 0.f);
    const bool vroi = (fabsf(r.x) + fabsf(r.y) + fabsf(r.z) + fabsf(r.w)) > 0.0f;
    const float rsum = (r.z - r.x) * (r.w - r.y) + 1e-8f;
    const int ncnt = __builtin_amdgcn_readfirstlane(s_cnt[0]);
    const int ccnt = __builtin_amdgcn_readfirstlane(s_cnt[1]);

    auto iou_of = [&](float4 gb, float ga) -> float {
        float yy1 = fmaxf(r.x, gb.x);
        float xx1 = fmaxf(r.y, gb.y);
        float yy2 = fminf(r.z, gb.z);
        float xx2 = fminf(r.w, gb.w);
        float inter = fmaxf(yy2 - yy1, 0.0f) * fmaxf(xx2 - xx1, 0.0f);
        return inter * __builtin_amdgcn_rcpf(rsum + ga - inter);
    };

    float ncm = 0.0f;
    {
        const int chunk = (((ncnt + 3) >> 2) + 3) & ~3;
        const int g0 = wave * chunk;
        const int g1 = min(ncnt, g0 + chunk);
        for (int g = g0; g < g1; ++g) ncm = fmaxf(ncm, iou_of(s_box[g], s_area[g]));
    }
    float cm = 0.0f;
    {
        const int chunkc = (((ccnt + 3) >> 2) + 3) & ~3;
        const int hi = GG - wave * chunkc;
        const int lo = max(GG - ccnt, hi - chunkc);
        for (int g = lo; g < hi; ++g) cm = fmaxf(cm, iou_of(s_box[g], s_area[g]));
    }
    s_ncm[wave][lane] = ncm;
    s_cm[wave][lane]  = cm;
    __syncthreads();
    if (wave == 0 && n < NN) {
        float a = fmaxf(fmaxf(s_ncm[0][lane], s_ncm[1][lane]),
                        fmaxf(s_ncm[2][lane], s_ncm[3][lane]));
        float c = fmaxf(fmaxf(s_cm[0][lane], s_cm[1][lane]),
                        fmaxf(s_cm[2][lane], s_cm[3][lane]));
        const float nc_max = vroi ? a : 0.0f;
        const float c_max  = vroi ? c : 0.0f;
        out[b * 2 * NN + n]      = nc_max;
        out[b * 2 * NN + NN + n] = c_max;
        const float pos = (vroi && nc_max >= 0.5f) ? 1.0f : 0.0f;
        const float neg = (vroi && nc_max < 0.5f && c_max < 0.001f) ? 1.0f : 0.0f;
        out[BB * 2 * NN + b * NN + n]           = pos;
        out[BB * 2 * NN + BB * NN + b * NN + n] = neg;
    }
}

extern "C" void kernel_launch(void* const* d_in, const int* in_sizes, int n_in,
                              void* d_out, int out_size, void* d_ws, size_t ws_size,
                              hipStream_t stream) {
    const float4* rois     = (const float4*)d_in[0];
    const int*    gt_ids   = (const int*)d_in[1];
    const float4* gt_boxes = (const float4*)d_in[2];
    float*        out      = (float*)d_out;

    if (ws_size >= (size_t)WS_NEEDED) {
        char* ws = (char*)d_ws;
        float4* ws_box   = (float4*)(ws + WS_BOX_OFF);
        float*  ws_area  = (float*)(ws + WS_AREA_OFF);
        int*    ws_cnt   = (int*)(ws + WS_CNT_OFF);

        compact_kernel<<<BB, 256, 0, stream>>>(gt_ids, gt_boxes, ws_box, ws_area, ws_cnt);
        dim3 grid((NN + 63) / 64, BB);
        det_main_kernel<<<grid, 64 * WAVES, 0, stream>>>(
            rois, ws_box, (const float4*)ws_area, ws_cnt, out);
    } else {
        dim3 grid((NN + 63) / 64, BB);
        det_assign_fallback<<<grid, 256, 0, stream>>>(rois, gt_ids, gt_boxes, out);
    }
}